// Round 2
// baseline (202.327 us; speedup 1.0000x reference)
//
#include <hip/hip_runtime.h>

// DynamicDilationUnfold: B=4, C=64, H=W=128, G=4, Cg=16, K=3, stride=1, pad=1.
// out[b][((g*Cg+cg)*K+kh)*K+kw][ho*Wo+wo], fp32.
//
// R6: store-burst overhaul. R4->R5 rewrote the whole read path with ZERO time
// delta -> read path exonerated. Invariant suspect: 8-B stores scattered over
// 36 planes (256-B dense segments, ~2.3 TB/s effective vs 6.7 TB/s fill on the
// same buffer). This version:
//   - tile 8x128 (FULL row), 256 thr, 4 wo/thread
//   - per plane: one global_store_dwordx4 per thread; a wave covers 2 full
//     rows = 1024 B fully contiguous; a block covers 4 KiB dense per plane
//   - store instruction count halves; every store is a 1-KiB aligned burst
//   - read path from R5 kept: float4 channel-interleaved LDS + XOR quad
//     swizzle; staged region 14x134 quads = 30 KB LDS, ~5 blocks/CU

constexpr int B  = 4;
constexpr int C  = 64;
constexpr int H  = 128;
constexpr int W  = 128;
constexpr int G  = 4;
constexpr int Cg = C / G;            // 16
constexpr int K  = 3;
constexpr int KK = K * K;
constexpr int Ho = 128;
constexpr int Wo = 128;
constexpr int HW = H * W;            // 16384
constexpr int HoWo = Ho * Wo;        // 16384

constexpr int TILE_H = 8;
constexpr int TILE_W = 128;          // full width -> dense per-plane writes
constexpr int CPB    = 4;            // channels per block (interleaved in LDS)
constexpr int REG_H  = TILE_H + 6;   // 14 rows (halo -1 .. +5; max idx 13)
constexpr int REG_W  = TILE_W + 6;   // 134 cols (max idx 133)
constexpr int NQUAD  = REG_H * REG_W;          // 1876 float4 quads
constexpr int NQUAD_PAD = (NQUAD + 7) & ~7;    // 1880 (swizzle is 8-quad local)
constexpr int NTHREADS  = 256;

// bijective quad swizzle (flips quad bits[2:0] with bits[4:2]); applied on
// BOTH the staging write and the gather read -> consistent. Breaks the
// stride-4-quad (16-dword) bank clustering of the per-subpixel b128 gather.
__device__ __forceinline__ int swz(int q) { return q ^ ((q >> 2) & 7); }

__global__ __launch_bounds__(NTHREADS, 5) void ddu_kernel(
    const float* __restrict__ x,      // (B, C, H, W)
    const float* __restrict__ dmap,   // (B, G, H, W)
    float* __restrict__ out)          // (B, C*K*K, Ho*Wo)
{
    __shared__ float4 lds4[NQUAD_PAD];           // 30,080 B

    const int tid   = threadIdx.x;
    const int bid   = blockIdx.x;                // 1024 = b(4) g(4) chunk(4) th(16)
    const int th    = bid & 15;
    const int chunk = (bid >> 4) & 3;
    const int g     = (bid >> 6) & 3;
    const int b     = bid >> 8;

    const int ho0 = th * TILE_H;

    const float* __restrict__ xg = x + (size_t)(b * C + g * Cg + chunk * CPB) * HW;

    // ---- stage: 4 per-channel dword loads -> one linear ds_write_b128 ----
    const int r_img0 = ho0 - 1;                  // cols start at image col -1
#pragma unroll
    for (int it = 0; it < (NQUAD + NTHREADS - 1) / NTHREADS; ++it) {
        const int p = it * NTHREADS + tid;
        if (p < NQUAD) {
            const int r  = p / REG_W;
            const int c  = p - r * REG_W;
            const int ir = r_img0 + r;
            const int ic = c - 1;
            float4 v = make_float4(0.f, 0.f, 0.f, 0.f);
            if ((unsigned)ir < (unsigned)H && (unsigned)ic < (unsigned)W) {
                const float* __restrict__ s = xg + ir * W + ic;
                v.x = s[0];
                v.y = s[HW];
                v.z = s[2 * HW];
                v.w = s[3 * HW];
            }
            lds4[swz(p)] = v;                    // zero halo == validity mask
        }
    }
    __syncthreads();

    // ---- compute: each thread owns 4 adjacent wo (each has its own d) ----
    const int wi4 = tid & 31;                    // 0..31 -> covers full row
    const int hi  = tid >> 5;                    // 0..7
    const int ho  = ho0 + hi;
    const int wo  = wi4 * 4;

    const float4 dq = *(const float4*)&dmap[(size_t)(b * G + g) * HoWo + ho * Wo + wo];
    float dd[4] = { dq.x, dq.y, dq.z, dq.w };

    float* __restrict__ outb = out
        + (size_t)((b * C + g * Cg + chunk * CPB) * KK) * HoWo
        + (size_t)(ho * Wo + wo);

    const float rowf = (float)hi;

#pragma unroll
    for (int kh = 0; kh < K; ++kh) {
        int   rr[4];
        float lh[4], mh[4];
#pragma unroll
        for (int sp = 0; sp < 4; ++sp) {
            const float ph = rowf + (float)kh * dd[sp];
            const int   r  = (int)ph;            // >= 0 (d > 0)
            rr[sp] = r;
            lh[sp] = ph - (float)r;
            mh[sp] = 1.f - lh[sp];
        }

#pragma unroll
        for (int kw = 0; kw < K; ++kw) {
            float rs[4][4];                      // [subpixel][channel]
#pragma unroll
            for (int sp = 0; sp < 4; ++sp) {
                const float pw = (float)(wo + sp) + (float)kw * dd[sp];
                const int   c  = (int)pw;
                const float lw = pw - (float)c;

                const int q = rr[sp] * REG_W + c;    // max 13*134+132; +REG_W+1 <= 1875
                const float4 v00 = lds4[swz(q)];
                const float4 v01 = lds4[swz(q + 1)];
                const float4 v10 = lds4[swz(q + REG_W)];
                const float4 v11 = lds4[swz(q + REG_W + 1)];

                const float a00 = mh[sp] * (1.f - lw);
                const float a01 = mh[sp] * lw;
                const float a10 = lh[sp] * (1.f - lw);
                const float a11 = lh[sp] * lw;

                rs[sp][0] = a00 * v00.x + a01 * v01.x + a10 * v10.x + a11 * v11.x;
                rs[sp][1] = a00 * v00.y + a01 * v01.y + a10 * v10.y + a11 * v11.y;
                rs[sp][2] = a00 * v00.z + a01 * v01.z + a10 * v10.z + a11 * v11.z;
                rs[sp][3] = a00 * v00.w + a01 * v01.w + a10 * v10.w + a11 * v11.w;
            }

            float* __restrict__ o = outb + (size_t)(kh * K + kw) * HoWo;
#pragma unroll
            for (int ch = 0; ch < CPB; ++ch) {
                *(float4*)(o + (size_t)ch * (KK * HoWo)) =
                    make_float4(rs[0][ch], rs[1][ch], rs[2][ch], rs[3][ch]);
            }
        }
    }
}

extern "C" void kernel_launch(void* const* d_in, const int* in_sizes, int n_in,
                              void* d_out, int out_size, void* d_ws, size_t ws_size,
                              hipStream_t stream) {
    const float* x    = (const float*)d_in[0];
    const float* dmap = (const float*)d_in[1];
    float* out = (float*)d_out;

    const int grid = B * G * (Cg / CPB) * (Ho / TILE_H);   // 1024
    ddu_kernel<<<grid, NTHREADS, 0, stream>>>(x, dmap, out);
}

// Round 3
// 180.947 us; speedup vs baseline: 1.1182x; 1.1182x over previous
//
#include <hip/hip_runtime.h>

// DynamicDilationUnfold: B=4, C=64, H=W=128, G=4, Cg=16, K=3, stride=1, pad=1.
// out[b][((g*Cg+cg)*K+kh)*K+kw][ho*Wo+wo], fp32.
//
// R7: write-stream overhaul. Evidence: R4(32w)=R5(24w)=76us across a total
// read-path rewrite; R6 (denser stores, 16w) = 106us ~ 1/occupancy; effective
// BW stuck at ~2.2 TB/s vs 6.7 fill => scattered-write drain wall, not reads,
// not VALU. All prior tiles emit <=4KiB runs/plane with all 576 planes active
// at once -> ~256B per DRAM pseudo-channel visit -> row thrash.
// This version: block = (b, 4ch-chunk, 32-row full-width tile).
//   - per (kh,kw) phase each block writes 16 KiB CONTIGUOUS per plane
//     (4 planes/block/phase), phases temporally clustered
//   - 84 KB LDS: 4ch x 39x135 f32 scalar layout; corner reads are the
//     R4-proven stride-2 ds_read2 pattern (2 lanes/bank = free, m136)
//   - grid 256 (1 block/CU), 512 thr = 8 waves/CU, __launch_bounds__(512,2)
//     -> 256 VGPR budget: latency hiding via ILP (compiler hoists the 16
//     independent corner reads per pixel) instead of TLP
// Discriminating outcomes: write theory right -> ~40-55us kernel;
// occupancy theory right -> kernel >89us and surfaces in top-5 WITH counters.

constexpr int B  = 4;
constexpr int C  = 64;
constexpr int H  = 128;
constexpr int W  = 128;
constexpr int G  = 4;
constexpr int Cg = C / G;            // 16
constexpr int K  = 3;
constexpr int KK = K * K;
constexpr int Ho = 128;
constexpr int Wo = 128;
constexpr int HW = H * W;
constexpr int HoWo = Ho * Wo;

constexpr int TILE_H = 32;           // rows per block, full 128-col width
constexpr int CPB    = 4;            // channels per block
constexpr int REG_H  = TILE_H + 7;   // 39: image rows ro0-1 .. ro0+37 (d<3 => floor(ph)+1 <= 37)
constexpr int REG_W  = 135;          // image cols -1 .. 133 (135 % 32 = 7, decorrelates banks)
constexpr int CH_STRIDE = REG_H * REG_W;      // 5265 dwords per channel
constexpr int STAGE_TOTAL = CPB * CH_STRIDE;  // 21060 dwords = 84,240 B
constexpr int NTHREADS = 512;

__global__ __launch_bounds__(NTHREADS, 2) void ddu_kernel(
    const float* __restrict__ x,      // (B, C, H, W)
    const float* __restrict__ dmap,   // (B, G, H, W)
    float* __restrict__ out)          // (B, C*K*K, Ho*Wo)
{
    __shared__ float lds[STAGE_TOTAL];           // 84,240 B -> 1 block/CU

    const int tid = threadIdx.x;
    const int bid = blockIdx.x;                  // 256 = b(4) g(4) cq(4) rt(4)
    const int rt  = bid & 3;
    const int cq  = (bid >> 2) & 3;
    const int g   = (bid >> 4) & 3;
    const int b   = bid >> 6;

    const int ro0 = rt * TILE_H;
    const int cgb = cq * CPB;

    const float* __restrict__ xg = x + (size_t)(b * C + g * Cg + cgb) * HW;

    // ---- stage: linear LDS fill, coalesced dword loads, zero halo ----
    for (int it = 0; it < (STAGE_TOTAL + NTHREADS - 1) / NTHREADS; ++it) {
        const int p = it * NTHREADS + tid;
        if (p < STAGE_TOTAL) {
            const int ch  = p / CH_STRIDE;
            const int rem = p - ch * CH_STRIDE;
            const int rr  = rem / REG_W;
            const int cc  = rem - rr * REG_W;
            const int ir  = ro0 - 1 + rr;
            const int ic  = cc - 1;
            float v = 0.f;
            if ((unsigned)ir < (unsigned)H && (unsigned)ic < (unsigned)W)
                v = xg[(size_t)ch * HW + ir * W + ic];
            lds[p] = v;                          // zero halo == validity mask
        }
    }
    __syncthreads();

    // ---- compute: wave w owns rows 4w..4w+3; lane owns wo {2i, 2i+1} ----
    const int lane = tid & 63;
    const int wave = tid >> 6;
    const int wo0  = lane * 2;

    const float* __restrict__ dmg = dmap + (size_t)(b * G + g) * HoWo;

    float2 dv[4];
    float* obase[4];
    int hoL[4];
#pragma unroll
    for (int rw = 0; rw < 4; ++rw) {
        hoL[rw] = wave * 4 + rw;                 // local row 0..31
        const int ho = ro0 + hoL[rw];
        dv[rw] = *(const float2*)&dmg[ho * Wo + wo0];
        obase[rw] = out + (size_t)(b * C + g * Cg + cgb) * KK * HoWo
                        + (size_t)(ho * Wo + wo0);
    }

#pragma unroll
    for (int kh = 0; kh < K; ++kh) {
        int   r0[4], r1[4];
        float lh0[4], mh0[4], lh1[4], mh1[4];
#pragma unroll
        for (int rw = 0; rw < 4; ++rw) {
            // region-row coordinate: row 0 == image row ro0-1; ph in [0,37)
            const float ph0 = (float)hoL[rw] + (float)kh * dv[rw].x;
            const float ph1 = (float)hoL[rw] + (float)kh * dv[rw].y;
            r0[rw] = (int)ph0; lh0[rw] = ph0 - (float)r0[rw]; mh0[rw] = 1.f - lh0[rw];
            r1[rw] = (int)ph1; lh1[rw] = ph1 - (float)r1[rw]; mh1[rw] = 1.f - lh1[rw];
        }
#pragma unroll
        for (int kw = 0; kw < K; ++kw) {
#pragma unroll
            for (int rw = 0; rw < 4; ++rw) {
                // region-col coordinate: col 0 == image col -1; pw in [0,134)
                const float pw0 = (float)wo0       + (float)kw * dv[rw].x;
                const float pw1 = (float)(wo0 + 1) + (float)kw * dv[rw].y;
                const int   c0  = (int)pw0;
                const int   c1  = (int)pw1;
                const float lw0 = pw0 - (float)c0;
                const float lw1 = pw1 - (float)c1;

                const float a00 = mh0[rw] * (1.f - lw0);
                const float a01 = mh0[rw] * lw0;
                const float a10 = lh0[rw] * (1.f - lw0);
                const float a11 = lh0[rw] * lw0;

                const float b00 = mh1[rw] * (1.f - lw1);
                const float b01 = mh1[rw] * lw1;
                const float b10 = lh1[rw] * (1.f - lw1);
                const float b11 = lh1[rw] * lw1;

                const int base0 = r0[rw] * REG_W + c0;   // <= 36*135+133; +REG_W+1 < 5265
                const int base1 = r1[rw] * REG_W + c1;

                float* __restrict__ o = obase[rw] + (size_t)(kh * K + kw) * HoWo;
#pragma unroll
                for (int ch = 0; ch < CPB; ++ch) {
                    const float* __restrict__ l = lds + ch * CH_STRIDE;
                    const float s0 = a00 * l[base0]         + a01 * l[base0 + 1]
                                   + a10 * l[base0 + REG_W] + a11 * l[base0 + REG_W + 1];
                    const float s1 = b00 * l[base1]         + b01 * l[base1 + 1]
                                   + b10 * l[base1 + REG_W] + b11 * l[base1 + REG_W + 1];
                    *(float2*)(o + (size_t)ch * KK * HoWo) = make_float2(s0, s1);
                }
            }
        }
    }
}

extern "C" void kernel_launch(void* const* d_in, const int* in_sizes, int n_in,
                              void* d_out, int out_size, void* d_ws, size_t ws_size,
                              hipStream_t stream) {
    const float* x    = (const float*)d_in[0];
    const float* dmap = (const float*)d_in[1];
    float* out = (float*)d_out;

    const int grid = B * G * (Cg / CPB) * (Ho / TILE_H);   // 256 = 1 block/CU
    ddu_kernel<<<grid, NTHREADS, 0, stream>>>(x, dmap, out);
}

// Round 4
// 164.263 us; speedup vs baseline: 1.2317x; 1.1016x over previous
//
#include <hip/hip_runtime.h>

// DynamicDilationUnfold: B=4, C=64, H=W=128, G=4, Cg=16, K=3, stride=1, pad=1.
// out[b][((g*Cg+cg)*K+kh)*K+kw][ho*Wo+wo], fp32.
//
// R8: combine the two proven-good factors, never yet combined:
//   occupancy ladder: 32w/256B=76us (R4) ~ 24w/256B=76us (R5),
//                     16w/4KiB=106us (R6), 8w/16KiB=91.5us (R7)
//   -> R7 beat R6 with HALF the waves: write-run size matters.
//   -> both 76us points are high-occupancy with tiny runs.
// This kernel: R4's exact per-thread work (P=72) and 32 waves/CU, but tile =
// 16x128 full-width with 1024 threads:
//   - per plane: each wave stores one full row = 512 B contiguous per
//     global_store_dwordx2; each block writes 8 KiB contiguous per plane
//     (32x R4's 256-B runs) -> clean A/B vs R4 where ONLY store-run
//     geometry changes
//   - __launch_bounds__(1024,8): 64-VGPR cap (R4's proven budget),
//     2 blocks/CU x 16 waves = 32 waves/CU, LDS 47.5 KB x 2 = 95 KB
//   - read path: R4's channel-planar scalar LDS (ds_read2 pairs), stride
//     135 (odd -> ~2-way conflicts, free per m136); read path proven
//     perf-irrelevant (R4==R5), chosen to minimize spill risk at 64 VGPR

constexpr int B  = 4;
constexpr int C  = 64;
constexpr int H  = 128;
constexpr int W  = 128;
constexpr int G  = 4;
constexpr int Cg = C / G;            // 16
constexpr int K  = 3;
constexpr int KK = K * K;
constexpr int Ho = 128;
constexpr int Wo = 128;
constexpr int HW = H * W;
constexpr int HoWo = Ho * Wo;

constexpr int TILE_H = 16;           // rows per block, full 128-col width
constexpr int CPB    = 4;            // channels per block
constexpr int REG_H  = 22;           // region rows: image ro0-1 .. ro0+20 (ph < 16-1+6 => floor<=20, +1 = 21)
constexpr int REG_W  = 134;          // region cols: image -1 .. 132 (pw < 127+6 => floor<=132, +1 = 133)
constexpr int LDS_STRIDE = 135;      // odd stride -> bank-decorrelated
constexpr int CH_STRIDE  = REG_H * LDS_STRIDE;   // 2970 dwords per channel
constexpr int NSTAGE     = CPB * CH_STRIDE;      // 11880 dwords = 47,520 B
constexpr int NTHREADS   = 1024;

__global__ __launch_bounds__(NTHREADS, 8) void ddu_kernel(
    const float* __restrict__ x,      // (B, C, H, W)
    const float* __restrict__ dmap,   // (B, G, H, W)
    float* __restrict__ out)          // (B, C*K*K, Ho*Wo)
{
    __shared__ float lds[NSTAGE];                // 47,520 B -> 2 blocks/CU

    const int tid = threadIdx.x;
    const int bid = blockIdx.x;                  // 512 = b(4) g(4) chunk(4) rt(8)
    const int rt    = bid & 7;
    const int chunk = (bid >> 3) & 3;
    const int g     = (bid >> 5) & 3;
    const int b     = bid >> 7;

    const int ro0 = rt * TILE_H;
    const int cgb = chunk * CPB;

    const float* __restrict__ xg = x + (size_t)(b * C + g * Cg + cgb) * HW;

    // ---- stage: channel-planar scalar LDS, coalesced dword loads, zero halo ----
#pragma unroll
    for (int it = 0; it < (NSTAGE + NTHREADS - 1) / NTHREADS; ++it) {
        const int p = it * NTHREADS + tid;
        if (p < NSTAGE) {
            const int ch  = p / CH_STRIDE;
            const int rem = p - ch * CH_STRIDE;
            const int rr  = rem / LDS_STRIDE;
            const int cc  = rem - rr * LDS_STRIDE;
            const int ir  = ro0 - 1 + rr;
            const int ic  = cc - 1;
            float v = 0.f;
            if ((unsigned)ir < (unsigned)H && (unsigned)ic < (unsigned)W && cc < REG_W)
                v = xg[(size_t)ch * HW + ir * W + ic];
            lds[p] = v;                          // zero halo == validity mask
        }
    }
    __syncthreads();

    // ---- compute: each thread owns 2 adjacent wo; wave = one full row ----
    const int wi2 = tid & 63;                    // wo-pair 0..63 (full 128 cols)
    const int hi  = tid >> 6;                    // 0..15
    const int ho  = ro0 + hi;
    const int wo  = wi2 * 2;

    const float2 dv = *(const float2*)&dmap[(size_t)(b * G + g) * HoWo + ho * Wo + wo];
    const float d0 = dv.x;
    const float d1 = dv.y;

    float* __restrict__ outb = out
        + (size_t)((b * C + g * Cg + cgb) * KK) * HoWo
        + (size_t)(ho * Wo + wo);

    const float col0 = (float)wo;                // region col of subpixel 0
    const float col1 = (float)(wo + 1);
    const float rowf = (float)hi;                // region row coordinate base

#pragma unroll
    for (int kh = 0; kh < K; ++kh) {
        const float ph0 = rowf + (float)kh * d0;
        const float ph1 = rowf + (float)kh * d1;
        const int   r0  = (int)ph0;              // <= 20
        const int   r1  = (int)ph1;
        const float lh0 = ph0 - (float)r0;
        const float lh1 = ph1 - (float)r1;
        const float mh0 = 1.f - lh0;
        const float mh1 = 1.f - lh1;

#pragma unroll
        for (int kw = 0; kw < K; ++kw) {
            const float pw0 = col0 + (float)kw * d0;
            const float pw1 = col1 + (float)kw * d1;
            const int   c0  = (int)pw0;          // <= 132
            const int   c1  = (int)pw1;
            const float lw0 = pw0 - (float)c0;
            const float lw1 = pw1 - (float)c1;

            const float a00 = mh0 * (1.f - lw0);
            const float a01 = mh0 * lw0;
            const float a10 = lh0 * (1.f - lw0);
            const float a11 = lh0 * lw0;

            const float b00 = mh1 * (1.f - lw1);
            const float b01 = mh1 * lw1;
            const float b10 = lh1 * (1.f - lw1);
            const float b11 = lh1 * lw1;

            const int base0 = r0 * LDS_STRIDE + c0;   // +LDS_STRIDE+1 <= 2969 < 2970
            const int base1 = r1 * LDS_STRIDE + c1;

            float* __restrict__ o = outb + (size_t)(kh * K + kw) * HoWo;

#pragma unroll
            for (int ch = 0; ch < CPB; ++ch) {
                const float* __restrict__ l  = lds + ch * CH_STRIDE;
                const float* __restrict__ l0 = l + base0;
                const float* __restrict__ l1 = l + base1;
                float2 v;
                v.x = a00 * l0[0] + a01 * l0[1]
                    + a10 * l0[LDS_STRIDE] + a11 * l0[LDS_STRIDE + 1];
                v.y = b00 * l1[0] + b01 * l1[1]
                    + b10 * l1[LDS_STRIDE] + b11 * l1[LDS_STRIDE + 1];
                *(float2*)(o + (size_t)ch * (KK * HoWo)) = v;
            }
        }
    }
}

extern "C" void kernel_launch(void* const* d_in, const int* in_sizes, int n_in,
                              void* d_out, int out_size, void* d_ws, size_t ws_size,
                              hipStream_t stream) {
    const float* x    = (const float*)d_in[0];
    const float* dmap = (const float*)d_in[1];
    float* out = (float*)d_out;

    const int grid = B * G * (Cg / CPB) * (Ho / TILE_H);   // 512 = 2 blocks/CU
    ddu_kernel<<<grid, NTHREADS, 0, stream>>>(x, dmap, out);
}